// Round 7
// baseline (5450.890 us; speedup 1.0000x reference)
//
#include <hip/hip_runtime.h>
#include <math.h>

#define kN 30000
#define kE 240000
#define kG 64
#define kHSZ (1 << 19)
#define kMB 64
#define kMT 1024
#define kNB 30       // ceil(kN/1024)
#define kTail 3072

typedef unsigned long long ull;
#define kDEAD (~0ULL)

// ---------------- atomic helpers ----------------
__device__ __forceinline__ int ald(const int* p) {
  return __hip_atomic_load(p, __ATOMIC_RELAXED, __HIP_MEMORY_SCOPE_AGENT);
}
__device__ __forceinline__ ull aldull(const ull* p) {
  return __hip_atomic_load(p, __ATOMIC_RELAXED, __HIP_MEMORY_SCOPE_AGENT);
}
__device__ __forceinline__ void astull(ull* p, ull v) {
  __hip_atomic_store(p, v, __ATOMIC_RELAXED, __HIP_MEMORY_SCOPE_AGENT);
}
__device__ __forceinline__ void aadd(int* p, int v) {
  __hip_atomic_fetch_add(p, v, __ATOMIC_RELAXED, __HIP_MEMORY_SCOPE_AGENT);
}
// WORKGROUP scope for the block-0 tail (exclusive owner after handoff acquire)
__device__ __forceinline__ ull wldull(const ull* p) {
  return __hip_atomic_load(p, __ATOMIC_RELAXED, __HIP_MEMORY_SCOPE_WORKGROUP);
}
__device__ __forceinline__ void wstull(ull* p, ull v) {
  __hip_atomic_store(p, v, __ATOMIC_RELAXED, __HIP_MEMORY_SCOPE_WORKGROUP);
}
__device__ __forceinline__ unsigned enc_f(float x) {
  unsigned u = __float_as_uint(x);
  return (u & 0x80000000u) ? ~u : (u | 0x80000000u);
}
__device__ __forceinline__ float dec_f(unsigned u) {
  u = (u & 0x80000000u) ? (u ^ 0x80000000u) : ~u;
  return __uint_as_float(u);
}

// centralized grid barrier: 64 co-resident WGs
__device__ __forceinline__ void round_bar(int* bar, int* gen) {
  __syncthreads();
  if (threadIdx.x == 0) {
    int g = ++(*gen);
    __hip_atomic_fetch_add(bar, 1, __ATOMIC_ACQ_REL, __HIP_MEMORY_SCOPE_AGENT);
    while (__hip_atomic_load(bar, __ATOMIC_ACQUIRE, __HIP_MEMORY_SCOPE_AGENT) < kMB * g)
      __builtin_amdgcn_s_sleep(2);
  }
  __syncthreads();
}

// ---------------- embed: z = x @ W_embed ----------------
__global__ __launch_bounds__(256) void k_embed(const float* __restrict__ x,
                                               const float* __restrict__ W,
                                               float* __restrict__ z) {
  __shared__ float sW[128 * 64];
  int tid = threadIdx.x;
  for (int i = tid; i < 128 * 64; i += 256) sW[i] = W[i];
  __syncthreads();
  int lane = tid & 63, sub = tid >> 6;
  int row0 = blockIdx.x * 16;
  for (int r = sub; r < 16; r += 4) {
    int n = row0 + r;
    if (n >= kN) continue;
    const float* xr = x + (size_t)n * 128;
    float acc = 0.f;
#pragma unroll
    for (int k = 0; k < 128; ++k) acc = fmaf(xr[k], sW[k * 64 + lane], acc);
    z[(size_t)n * 64 + lane] = acc;
  }
}

// ---------------- per-layer init ----------------
__global__ void k_init(int* __restrict__ cluster, int* __restrict__ partner,
                       float* __restrict__ mult, double* __restrict__ den,
                       ull* __restrict__ P, int* __restrict__ deg,
                       int* __restrict__ cnt, int* __restrict__ ctrl,
                       int* __restrict__ hkey, int* __restrict__ hmin,
                       float* __restrict__ embs, int layer1) {
  int S = gridDim.x * blockDim.x;
  for (int i = blockIdx.x * blockDim.x + threadIdx.x; i < kHSZ; i += S) {
    if (i < kN) {
      cluster[i] = i;
      partner[i] = -1;
      mult[i] = 1.f;
      den[i] = 0.0;
      deg[i] = 0;
    }
    if (i < 2 * kN) P[i] = 0ULL;
    if (i < 16384) cnt[i] = 0;
    if (i < 8) ctrl[i] = 0;
    if (layer1) {
      hkey[i] = -1;
      hmin[i] = 0x7fffffff;
      if (i < 3 * kG * 64) embs[i] = 0.f;
    }
  }
}

// ---------------- per-node half-dots ----------------
__global__ __launch_bounds__(1024) void k_ab(const float* __restrict__ z,
                                             const float* __restrict__ We,
                                             int layer, float* __restrict__ a,
                                             float* __restrict__ b) {
  int wid = (blockIdx.x * 1024 + threadIdx.x) >> 6;
  int lane = threadIdx.x & 63;
  int nw = (gridDim.x * 1024) >> 6;
  float wlo = We[layer * 128 + lane];
  float whi = We[layer * 128 + 64 + lane];
  for (int n = wid; n < kN; n += nw) {
    float zv = z[(size_t)n * 64 + lane];
    float fa = zv * wlo, fb = zv * whi;
#pragma unroll
    for (int m = 32; m > 0; m >>= 1) {
      fa += __shfl_xor(fa, m, 64);
      fb += __shfl_xor(fb, m, 64);
    }
    if (lane == 0) {
      a[n] = fa;
      b[n] = fb;
    }
  }
}

// ---------------- raw edge score + f64 denominator ----------------
__global__ void k_rawe(const float* __restrict__ a, const float* __restrict__ b,
                       const float* __restrict__ be, int layer,
                       const int* __restrict__ esrc, const int* __restrict__ edst,
                       const int* __restrict__ emask, float* __restrict__ raws,
                       double* __restrict__ den) {
  int e = blockIdx.x * 256 + threadIdx.x;
  if (e >= kE) return;
  if (emask && !emask[e]) return;
  int t = edst[e];
  float raw = a[esrc[e]] + b[t] + be[layer];
  raws[e] = raw;
  atomicAdd(&den[t], exp((double)raw));
}

// ---------------- edge key + degree count ----------------
// key = enc(score) << 18 | (262143 - e); unique per edge; DEAD/0 unreachable.
__global__ void k_key(const float* __restrict__ raws, const double* __restrict__ den,
                      const int* __restrict__ esrc, const int* __restrict__ edst,
                      const int* __restrict__ emask, ull* __restrict__ ekey,
                      int* __restrict__ deg) {
  int e = blockIdx.x * 256 + threadIdx.x;
  if (e >= kE) return;
  if (emask && !emask[e]) return;
  int s = esrc[e], t = edst[e];
  double ex = exp((double)raws[e]);
  float ep = (float)(ex / den[t]) + 0.5f;
  ekey[e] = ((ull)enc_f(ep) << 18) | (ull)(262143 - e);
  atomicAdd(&deg[s], 1);
  if (t != s) atomicAdd(&deg[t], 1);
}

// ---------------- prefix scan (3-phase) -> rowptr, fill ----------------
__global__ __launch_bounds__(1024) void k_s1(const int* __restrict__ deg,
                                             int* __restrict__ tmp,
                                             int* __restrict__ bsum) {
  __shared__ int sd[1024];
  int tid = threadIdx.x;
  int g = blockIdx.x * 1024 + tid;
  sd[tid] = (g < kN) ? deg[g] : 0;
  __syncthreads();
  for (int o = 1; o < 1024; o <<= 1) {
    int t = (tid >= o) ? sd[tid - o] : 0;
    __syncthreads();
    sd[tid] += t;
    __syncthreads();
  }
  tmp[g] = sd[tid];
  if (tid == 1023) bsum[blockIdx.x] = sd[1023];
}
__global__ void k_s2(int* __restrict__ bsum, int* __restrict__ rowptr) {
  if (threadIdx.x == 0) {
    int run = 0;
    for (int b = 0; b < kNB; ++b) {
      int t = bsum[b];
      bsum[b] = run;
      run += t;
    }
    rowptr[kN] = run;
  }
}
__global__ __launch_bounds__(1024) void k_s3(const int* __restrict__ deg,
                                             const int* __restrict__ tmp,
                                             const int* __restrict__ bsum,
                                             int* __restrict__ rowptr,
                                             int* __restrict__ fill) {
  int g = blockIdx.x * 1024 + threadIdx.x;
  if (g >= kN) return;
  int ex = bsum[blockIdx.x] + tmp[g] - deg[g];
  rowptr[g] = ex;
  fill[g] = ex;
}

// ---------------- scatter edges into CSR adjacency ----------------
__global__ void k_scatter(const int* __restrict__ esrc, const int* __restrict__ edst,
                          const int* __restrict__ emask, const ull* __restrict__ ekey,
                          int* __restrict__ fill, ull* __restrict__ akey,
                          int* __restrict__ aoth) {
  int e = blockIdx.x * 256 + threadIdx.x;
  if (e >= kE) return;
  if (emask && !emask[e]) return;
  int s = esrc[e], t = edst[e];
  ull key = ekey[e];
  int ps = atomicAdd(&fill[s], 1);
  akey[ps] = key;
  aoth[ps] = t;
  if (t != s) {
    int pt = atomicAdd(&fill[t], 1);
    akey[pt] = key;
    aoth[pt] = s;
  }
}

// ---------------- node-centric mutual-proposal matching ----------------
// P is parity-split: round r reads P[(r-1)&1], writes P[r&1]. Each live node:
// 1 AGENT load + 1 AGENT store per round. DEAD written to both parities over
// two rounds (never to the parity being read this round).
__global__ __launch_bounds__(kMT) void k_matchn(
    const int* __restrict__ esrc, const int* __restrict__ edst,
    const ull* __restrict__ akey, int* __restrict__ aoth,
    const int* __restrict__ rowptr, ull* __restrict__ P, int* __restrict__ cnt,
    int* __restrict__ ctrl, int2* __restrict__ tail, int* __restrict__ cluster,
    int* __restrict__ partner, float* __restrict__ mult) {
  const int tid = threadIdx.x;
  const int gtid = blockIdx.x * kMT + tid;
  const int lane = tid & 63;
  int gen = 0;
  const int n = gtid;
  const bool owner = (n < kN);
  int rs = 0, re = 0, ci = -1, oth = -1, pend = 0;
  ull key = 0;
  bool alive = false;

  // ---- round 0: initial proposal = max key in my segment ----
  if (owner) {
    rs = rowptr[n];
    re = rowptr[n + 1];
    ull bk = 0;
    int bj = -1;
    for (int j = rs; j < re; ++j) {
      ull k2 = akey[j];
      if (k2 > bk) { bk = k2; bj = j; }
    }
    if (bj >= 0) {
      ci = bj; key = bk; oth = aoth[bj];
      alive = true;
      astull(&P[n], key);  // parity 0
    }
  }
  {
    int a = alive ? 1 : 0;
#pragma unroll
    for (int m = 32; m; m >>= 1) a += __shfl_xor(a, m, 64);
    if (lane == 0 && a) aadd(&cnt[0], a);
  }

  int r = 1;
  bool to_tail = false;
  for (; r < 16000; ++r) {
    round_bar(&ctrl[0], &gen);
    int tot = ald(&cnt[r - 1]);
    if (tot == 0) return;
    if (tot < kTail) { to_tail = true; break; }
    ull* Pprev = P + (size_t)((r - 1) & 1) * kN;
    ull* Pcur = P + (size_t)(r & 1) * kN;
    if (owner) {
      if (pend) {
        astull(&Pcur[n], kDEAD);  // second parity of the death marker
        pend = 0;
      } else if (alive) {
        ull bp = aldull(&Pprev[oth]);  // self-loop: reads own key -> match
        if (bp == key) {
          // ---- matched ----
          int e = 262143 - (int)(key & 0x3FFFF);
          int s = esrc[e], t = edst[e];
          float ep = dec_f((unsigned)(key >> 18));
          if (n == s) { partner[s] = t; mult[s] = ep; }
          if (n == t) cluster[t] = s;
          alive = false;
          astull(&Pcur[n], kDEAD);
          pend = 1;
        } else if (bp == kDEAD) {
          // ---- target died: mark entry, rescan (<=4 liveness probes) ----
          aoth[ci] = -1;
          for (int probe = 0; probe < 5 && alive; ++probe) {
            ull bk = 0;
            int bj = -1;
            for (int j = rs; j < re; ++j) {
              if (aoth[j] >= 0) {
                ull k2 = akey[j];
                if (k2 > bk) { bk = k2; bj = j; }
              }
            }
            if (bj < 0) { alive = false; break; }  // inert: no live neighbors
            if (probe == 4) { ci = bj; key = bk; oth = aoth[bj]; break; }
            ull q = aldull(&Pprev[aoth[bj]]);
            if (q == kDEAD) { aoth[bj] = -1; continue; }
            ci = bj; key = bk; oth = aoth[bj];
            break;
          }
          if (alive) astull(&Pcur[n], key);
        } else {
          astull(&Pcur[n], key);  // keep proposing
        }
      }
    }
    int a = (owner && alive) ? 1 : 0;
#pragma unroll
    for (int m = 32; m; m >>= 1) a += __shfl_xor(a, m, 64);
    if (lane == 0 && a) aadd(&cnt[r], a);
  }
  if (!to_tail) return;

  // ---- handoff: flush pending deaths, compact live nodes ----
  if (owner && pend) astull(&P[(size_t)(r & 1) * kN + n], kDEAD);
  {
    bool act = owner && alive;
    unsigned long long mb = __ballot(act);
    if (mb) {
      int leader = __ffsll(mb) - 1;
      int base = 0;
      if (lane == leader)
        base = __hip_atomic_fetch_add(&ctrl[1], (int)__popcll(mb), __ATOMIC_RELAXED,
                                      __HIP_MEMORY_SCOPE_AGENT);
      base = __shfl(base, leader, 64);
      if (act) tail[base + __popcll(mb & ((1ULL << lane) - 1))] = make_int2(n, ci);
    }
  }
  round_bar(&ctrl[0], &gen);  // AGENT acquire: block 0 sees all prior state
  if (blockIdx.x != 0) return;

  // ---- tail: block 0 alone, WG-scope, 2-phase rounds ----
  __shared__ int ls;
  int m = ald(&ctrl[1]);
  int tn[4], tci[4], toth[4], trs[4], tre[4];
  ull tkey[4];
  bool tal[4];
#pragma unroll
  for (int k = 0; k < 4; ++k) {
    tal[k] = false;
    int idx = tid + k * kMT;
    if (idx < m) {
      int2 E = tail[idx];
      tn[k] = E.x;
      tci[k] = E.y;
      tkey[k] = akey[E.y];
      toth[k] = aoth[E.y];
      trs[k] = rowptr[E.x];
      tre[k] = rowptr[E.x + 1];
      tal[k] = true;
    }
  }
  int live = m;
  for (int rr = r; live > 0 && rr < 32000; ++rr) {
    ull* Pprev = P + (size_t)((rr - 1) & 1) * kN;
    ull* Pcur = P + (size_t)(rr & 1) * kN;
    int dec[4];  // 0 keep, 1 match, 2 inert
#pragma unroll
    for (int k = 0; k < 4; ++k) {
      dec[k] = 0;
      if (!tal[k]) continue;
      ull bp = wldull(&Pprev[toth[k]]);
      if (bp == tkey[k]) {
        dec[k] = 1;
      } else if (bp == kDEAD) {
        aoth[tci[k]] = -1;
        bool al = true;
        for (int probe = 0; probe < 5; ++probe) {
          ull bk = 0;
          int bj = -1;
          for (int j = trs[k]; j < tre[k]; ++j) {
            if (aoth[j] >= 0) {
              ull k2 = akey[j];
              if (k2 > bk) { bk = k2; bj = j; }
            }
          }
          if (bj < 0) { al = false; break; }
          if (probe == 4) { tci[k] = bj; tkey[k] = bk; toth[k] = aoth[bj]; break; }
          ull q = wldull(&Pprev[aoth[bj]]);
          if (q == kDEAD) { aoth[bj] = -1; continue; }
          tci[k] = bj; tkey[k] = bk; toth[k] = aoth[bj];
          break;
        }
        if (!al) dec[k] = 2;
      }
    }
    __syncthreads();
    if (tid == 0) ls = 0;
    __syncthreads();
    int myl = 0;
#pragma unroll
    for (int k = 0; k < 4; ++k) {
      if (!tal[k]) continue;
      if (dec[k] == 1) {
        int e = 262143 - (int)(tkey[k] & 0x3FFFF);
        int s = esrc[e], t = edst[e];
        float ep = dec_f((unsigned)(tkey[k] >> 18));
        if (tn[k] == s) { partner[s] = t; mult[s] = ep; }
        if (tn[k] == t) cluster[t] = s;
        wstull(&Pcur[tn[k]], kDEAD);
        wstull(&Pprev[tn[k]], kDEAD);
        tal[k] = false;
      } else if (dec[k] == 2) {
        tal[k] = false;  // inert: no live neighbors -> no readers
      } else {
        wstull(&Pcur[tn[k]], tkey[k]);
        ++myl;
      }
    }
#pragma unroll
    for (int mm = 32; mm; mm >>= 1) myl += __shfl_xor(myl, mm, 64);
    if (lane == 0 && myl) atomicAdd(&ls, myl);
    __syncthreads();
    live = ls;
  }
}

// ---------------- fused merged-features + graph pooling ----------------
__global__ __launch_bounds__(256) void k_newx_pool(
    const float* __restrict__ z, const int* __restrict__ cluster,
    const int* __restrict__ partner, const float* __restrict__ mult,
    const int* __restrict__ batch, float* __restrict__ zo,
    float* __restrict__ embs_g) {
  int tid = threadIdx.x;
  int d = tid & 63;
  int n0 = blockIdx.x * 128 + (tid >> 6) * 32;
  float acc = 0.f;
  int curg = -1;
  for (int k = 0; k < 32; ++k) {
    int n = n0 + k;
    if (n >= kN) break;
    int g = batch[n];
    if (g != curg) {
      if (curg >= 0 && acc != 0.f) atomicAdd(&embs_g[curg * 64 + d], acc);
      acc = 0.f;
      curg = g;
    }
    float v;
    if (cluster) {
      v = 0.f;
      if (cluster[n] == n) {
        v = z[(size_t)n * 64 + d];
        int p = partner[n];
        if (p >= 0 && p != n) v += z[(size_t)p * 64 + d];
        v *= mult[n];
      }
    } else {
      v = z[(size_t)n * 64 + d];
    }
    if (zo) zo[(size_t)n * 64 + d] = v;
    acc += v;
  }
  if (curg >= 0 && acc != 0.f) atomicAdd(&embs_g[curg * 64 + d], acc);
}

// ---------------- edge remap + hash-dedup ----------------
__global__ void k_remap(const int* __restrict__ esrc, const int* __restrict__ edst,
                        const int* __restrict__ cluster, const int* __restrict__ emask,
                        int* __restrict__ esrcn, int* __restrict__ edstn,
                        int* __restrict__ hkey, int* __restrict__ hmin,
                        int* __restrict__ hslot) {
  int e = blockIdx.x * 256 + threadIdx.x;
  if (e >= kE) return;
  int ns = cluster[esrc[e]];
  int nt = cluster[edst[e]];
  esrcn[e] = ns;
  edstn[e] = nt;
  if (emask && !emask[e]) return;
  int key = ns * kN + nt;
  unsigned h = (((unsigned)key * 2654435761u) >> 13) & (kHSZ - 1);
  while (true) {
    int old = atomicCAS(&hkey[h], -1, key);
    if (old == -1 || old == key) break;
    h = (h + 1) & (kHSZ - 1);
  }
  atomicMin(&hmin[h], e);
  hslot[e] = (int)h;
}

__global__ void k_dedup(const int* __restrict__ emask, const int* __restrict__ hmin,
                        const int* __restrict__ hslot, int* __restrict__ emaskn) {
  int e = blockIdx.x * 256 + threadIdx.x;
  if (e >= kE) return;
  int keep = 0;
  if (!emask || emask[e]) keep = (hmin[hslot[e]] == e) ? 1 : 0;
  emaskn[e] = keep;
}

// ---------------- final FC ----------------
__global__ void k_final(const float* __restrict__ embs, const float* __restrict__ Wfc,
                        const float* __restrict__ bfc, float* __restrict__ out) {
  int tid = threadIdx.x;
  if (tid >= kG * 10) return;
  int g = tid / 10, c = tid % 10;
  float acc = bfc[c];
  for (int l = 0; l < 3; ++l)
    for (int d = 0; d < 64; ++d)
      acc += embs[l * (kG * 64) + g * 64 + d] * Wfc[(l * 64 + d) * 10 + c];
  out[g * 10 + c] = acc;
}

extern "C" void kernel_launch(void* const* d_in, const int* in_sizes, int n_in,
                              void* d_out, int out_size, void* d_ws, size_t ws_size,
                              hipStream_t stream) {
  (void)in_sizes; (void)n_in; (void)out_size; (void)ws_size;
  const float* x = (const float*)d_in[0];
  const int* ei = (const int*)d_in[1];
  const int* batch = (const int*)d_in[2];
  const float* Wemb = (const float*)d_in[3];
  const float* We = (const float*)d_in[4];
  const float* be = (const float*)d_in[5];
  const float* Wfc = (const float*)d_in[6];
  const float* bfc = (const float*)d_in[7];
  float* out = (float*)d_out;

  char* ws = (char*)d_ws;
  size_t off = 0;
  auto alloc = [&](size_t bytes) -> void* {
    void* p = ws + off;
    off = (off + bytes + 255) & ~(size_t)255;
    return p;
  };
  float* z0 = (float*)alloc((size_t)kN * 64 * 4);
  float* z1 = (float*)alloc((size_t)kN * 64 * 4);
  float* raws = (float*)alloc((size_t)kE * 4);
  float* an = (float*)alloc((size_t)kN * 4);
  float* bn = (float*)alloc((size_t)kN * 4);
  double* den = (double*)alloc((size_t)kN * 8);
  ull* P = (ull*)alloc((size_t)2 * kN * 8);
  ull* ekey = (ull*)alloc((size_t)kE * 8);
  ull* akey = (ull*)alloc((size_t)2 * kE * 8);
  int* aoth = (int*)alloc((size_t)2 * kE * 4);
  int* deg = (int*)alloc((size_t)kN * 4);
  int* rowptr = (int*)alloc((size_t)(kN + 1) * 4);
  int* fill = (int*)alloc((size_t)kN * 4);
  int* tmp = (int*)alloc((size_t)kNB * 1024 * 4);
  int* bsum = (int*)alloc((size_t)kNB * 4);
  int* cluster = (int*)alloc((size_t)kN * 4);
  int* partner = (int*)alloc((size_t)kN * 4);
  float* mult = (float*)alloc((size_t)kN * 4);
  int* esrc1 = (int*)alloc((size_t)kE * 4);
  int* edst1 = (int*)alloc((size_t)kE * 4);
  int* emask1 = (int*)alloc((size_t)kE * 4);
  int2* tail = (int2*)alloc((size_t)4096 * 8);
  int* hkey = (int*)alloc((size_t)kHSZ * 4);
  int* hmin = (int*)alloc((size_t)kHSZ * 4);
  int* hslot = (int*)alloc((size_t)kE * 4);
  float* embs = (float*)alloc((size_t)3 * kG * 64 * 4);
  int* cnt = (int*)alloc((size_t)16384 * 4);
  int* ctrl = (int*)alloc(256);

  const int gE = (kE + 255) / 256;   // 938
  const int gNP = (kN + 127) / 128;  // 235

  // ---------------- layer 1 ----------------
  k_init<<<512, 256, 0, stream>>>(cluster, partner, mult, den, P, deg, cnt, ctrl,
                                  hkey, hmin, embs, 1);
  k_embed<<<kN / 16, 256, 0, stream>>>(x, Wemb, z0);
  k_newx_pool<<<gNP, 256, 0, stream>>>(z0, nullptr, nullptr, nullptr, batch, nullptr,
                                       embs);
  k_ab<<<480, 1024, 0, stream>>>(z0, We, 0, an, bn);
  k_rawe<<<gE, 256, 0, stream>>>(an, bn, be, 0, ei, ei + kE, nullptr, raws, den);
  k_key<<<gE, 256, 0, stream>>>(raws, den, ei, ei + kE, nullptr, ekey, deg);
  k_s1<<<kNB, 1024, 0, stream>>>(deg, tmp, bsum);
  k_s2<<<1, 64, 0, stream>>>(bsum, rowptr);
  k_s3<<<kNB, 1024, 0, stream>>>(deg, tmp, bsum, rowptr, fill);
  k_scatter<<<gE, 256, 0, stream>>>(ei, ei + kE, nullptr, ekey, fill, akey, aoth);
  k_matchn<<<kMB, kMT, 0, stream>>>(ei, ei + kE, akey, aoth, rowptr, P, cnt, ctrl,
                                    tail, cluster, partner, mult);
  k_newx_pool<<<gNP, 256, 0, stream>>>(z0, cluster, partner, mult, batch, z1,
                                       embs + kG * 64);
  k_remap<<<gE, 256, 0, stream>>>(ei, ei + kE, cluster, nullptr, esrc1, edst1, hkey,
                                  hmin, hslot);
  k_dedup<<<gE, 256, 0, stream>>>(nullptr, hmin, hslot, emask1);

  // ---------------- layer 2 ----------------
  k_init<<<512, 256, 0, stream>>>(cluster, partner, mult, den, P, deg, cnt, ctrl,
                                  hkey, hmin, embs, 0);
  k_ab<<<480, 1024, 0, stream>>>(z1, We, 1, an, bn);
  k_rawe<<<gE, 256, 0, stream>>>(an, bn, be, 1, esrc1, edst1, emask1, raws, den);
  k_key<<<gE, 256, 0, stream>>>(raws, den, esrc1, edst1, emask1, ekey, deg);
  k_s1<<<kNB, 1024, 0, stream>>>(deg, tmp, bsum);
  k_s2<<<1, 64, 0, stream>>>(bsum, rowptr);
  k_s3<<<kNB, 1024, 0, stream>>>(deg, tmp, bsum, rowptr, fill);
  k_scatter<<<gE, 256, 0, stream>>>(esrc1, edst1, emask1, ekey, fill, akey, aoth);
  k_matchn<<<kMB, kMT, 0, stream>>>(esrc1, edst1, akey, aoth, rowptr, P, cnt, ctrl,
                                    tail, cluster, partner, mult);
  k_newx_pool<<<gNP, 256, 0, stream>>>(z1, cluster, partner, mult, batch, nullptr,
                                       embs + 2 * kG * 64);

  k_final<<<1, 640, 0, stream>>>(embs, Wfc, bfc, out);
}

// Round 8
// 2903.025 us; speedup vs baseline: 1.8777x; 1.8777x over previous
//
#include <hip/hip_runtime.h>
#include <math.h>

#define kN 30000
#define kE 240000
#define kG 64
#define kHSZ (1 << 19)
#define kNW 938   // ceil(30000/32)
#define kMT 1024
#define kSlices 235  // ceil(kE / kMT)

typedef unsigned long long ull;

__device__ __forceinline__ unsigned enc_f(float x) {
  unsigned u = __float_as_uint(x);
  return (u & 0x80000000u) ? ~u : (u | 0x80000000u);
}
__device__ __forceinline__ float dec_f(unsigned u) {
  u = (u & 0x80000000u) ? (u ^ 0x80000000u) : ~u;
  return __uint_as_float(u);
}

// ---------------- embed: z = x @ W_embed ----------------
__global__ __launch_bounds__(256) void k_embed(const float* __restrict__ x,
                                               const float* __restrict__ W,
                                               float* __restrict__ z) {
  __shared__ float sW[128 * 64];
  int tid = threadIdx.x;
  for (int i = tid; i < 128 * 64; i += 256) sW[i] = W[i];
  __syncthreads();
  int lane = tid & 63, sub = tid >> 6;
  int row0 = blockIdx.x * 16;
  for (int r = sub; r < 16; r += 4) {
    int n = row0 + r;
    if (n >= kN) continue;
    const float* xr = x + (size_t)n * 128;
    float acc = 0.f;
#pragma unroll
    for (int k = 0; k < 128; ++k) acc = fmaf(xr[k], sW[k * 64 + lane], acc);
    z[(size_t)n * 64 + lane] = acc;
  }
}

// ---------------- per-layer init ----------------
__global__ void k_init(int* __restrict__ cluster, int* __restrict__ partner,
                       float* __restrict__ mult, double* __restrict__ den,
                       int* __restrict__ cnt, int* __restrict__ hkey,
                       int* __restrict__ hmin, float* __restrict__ embs,
                       int layer1) {
  int S = gridDim.x * blockDim.x;
  for (int i = blockIdx.x * blockDim.x + threadIdx.x; i < kHSZ; i += S) {
    if (i < kN) {
      cluster[i] = i;
      partner[i] = -1;
      mult[i] = 1.f;
      den[i] = 0.0;
    }
    if (i < 8) cnt[i] = 0;
    if (layer1) {
      hkey[i] = -1;
      hmin[i] = 0x7fffffff;
      if (i < 3 * kG * 64) embs[i] = 0.f;
    }
  }
}

// ---------------- per-node half-dots ----------------
__global__ __launch_bounds__(1024) void k_ab(const float* __restrict__ z,
                                             const float* __restrict__ We,
                                             int layer, float* __restrict__ a,
                                             float* __restrict__ b) {
  int wid = (blockIdx.x * 1024 + threadIdx.x) >> 6;
  int lane = threadIdx.x & 63;
  int nw = (gridDim.x * 1024) >> 6;
  float wlo = We[layer * 128 + lane];
  float whi = We[layer * 128 + 64 + lane];
  for (int n = wid; n < kN; n += nw) {
    float zv = z[(size_t)n * 64 + lane];
    float fa = zv * wlo, fb = zv * whi;
#pragma unroll
    for (int m = 32; m > 0; m >>= 1) {
      fa += __shfl_xor(fa, m, 64);
      fb += __shfl_xor(fb, m, 64);
    }
    if (lane == 0) {
      a[n] = fa;
      b[n] = fb;
    }
  }
}

// ---------------- raw edge score + f64 denominator (no-max softmax) ----------
__global__ void k_rawe(const float* __restrict__ a, const float* __restrict__ b,
                       const float* __restrict__ be, int layer,
                       const int* __restrict__ esrc, const int* __restrict__ edst,
                       const int* __restrict__ emask, float* __restrict__ raws,
                       double* __restrict__ den) {
  int e = blockIdx.x * 256 + threadIdx.x;
  if (e >= kE) return;
  if (emask && !emask[e]) return;
  int t = edst[e];
  float raw = a[esrc[e]] + b[t] + be[layer];
  raws[e] = raw;
  atomicAdd(&den[t], exp((double)raw));  // |raw| << 709: no overflow
}

// ---------------- score + initial worklist (wave-aggregated append) ----------
// record: {st = s | t<<16, e, enc, 0}
__global__ void k_score(const float* __restrict__ raws, const double* __restrict__ den,
                        const int* __restrict__ esrc, const int* __restrict__ edst,
                        const int* __restrict__ emask, int4* __restrict__ wl,
                        int* __restrict__ cnt) {
  int e = blockIdx.x * 256 + threadIdx.x;
  int lane = threadIdx.x & 63;
  bool live = false;
  int st = 0;
  unsigned u = 0;
  if (e < kE && (!emask || emask[e])) {
    int s = esrc[e], t = edst[e];
    double ex = exp((double)raws[e]);
    float ep = (float)(ex / den[t]) + 0.5f;
    u = enc_f(ep);
    st = s | (t << 16);
    live = true;
  }
  ull mb = __ballot(live);
  if (mb) {
    int leader = __ffsll(mb) - 1;
    int base = 0;
    if (lane == leader) base = atomicAdd(cnt, __popcll(mb));
    base = __shfl(base, leader, 64);
    if (live)
      wl[base + __popcll(mb & ((1ULL << lane) - 1))] = make_int4(st, e, (int)u, 0);
  }
}

// ---------------- matching: single-WG, all state in LDS ----------------------
// best[30000] (u32) + avail bitmask in dynamic LDS (~124KB). Per round:
//  A: ds atomicMax enc per endpoint of live edges
//  B: classify candidates (best==enc at both ends) into register bitmasks
//  C: candidates ds atomicMin edge-id into the same cells (id < 2^18 < enc)
//  D: match iff both cells == id  -> exact (score desc, id asc) greedy
//  E: compact survivors into next worklist; reset touched best cells
__global__ __launch_bounds__(kMT) void k_matchL(int4* __restrict__ wlA,
                                                int4* __restrict__ wlB,
                                                const int* __restrict__ cnt,
                                                int* __restrict__ cluster,
                                                int* __restrict__ partner,
                                                float* __restrict__ mult) {
  extern __shared__ unsigned dsm[];
  unsigned* best = dsm;         // [kN]
  unsigned* avail = dsm + kN;   // [kNW]
  __shared__ int sh_n, sh_out;
  const int tid = threadIdx.x;
  const int lane = tid & 63;

  for (int i = tid; i < kN; i += kMT) best[i] = 0u;
  for (int w = tid; w < kNW; w += kMT) {
    int rem = kN - (w << 5);
    avail[w] = (rem >= 32) ? 0xFFFFFFFFu : ((1u << rem) - 1u);
  }
  if (tid == 0) sh_n = cnt[0];
  __syncthreads();
  int n = sh_n;
  int4* cur = wlA;
  int4* nxt = wlB;

  for (int round = 0; round < 4000 && n > 0; ++round) {
    const int K = (n + kMT - 1) / kMT;
    // ---- A: post enc maxima ----
    for (int k = 0; k < K; ++k) {
      int i = tid + k * kMT;
      if (i < n) {
        int4 q = cur[i];
        int s = q.x & 0xFFFF, t = q.x >> 16;
        if (((avail[s >> 5] >> (s & 31)) & 1u) &&
            ((avail[t >> 5] >> (t & 31)) & 1u)) {
          unsigned u = (unsigned)q.z;
          atomicMax(&best[s], u);
          if (t != s) atomicMax(&best[t], u);
        }
      }
    }
    __syncthreads();
    // ---- B: classify into register bitmasks ----
    ull liveM[4] = {0, 0, 0, 0}, candM[4] = {0, 0, 0, 0}, matM[4] = {0, 0, 0, 0};
    for (int k = 0; k < K; ++k) {
      int i = tid + k * kMT;
      if (i < n) {
        int4 q = cur[i];
        int s = q.x & 0xFFFF, t = q.x >> 16;
        if (((avail[s >> 5] >> (s & 31)) & 1u) &&
            ((avail[t >> 5] >> (t & 31)) & 1u)) {
          liveM[k >> 6] |= 1ULL << (k & 63);
          unsigned u = (unsigned)q.z;
          if (best[s] == u && best[t] == u) candM[k >> 6] |= 1ULL << (k & 63);
        }
      }
    }
    __syncthreads();
    // ---- C: tie-resolve by min edge id ----
    for (int k = 0; k < K; ++k) {
      if ((candM[k >> 6] >> (k & 63)) & 1ULL) {
        int4 q = cur[tid + k * kMT];
        int s = q.x & 0xFFFF, t = q.x >> 16;
        atomicMin(&best[s], (unsigned)q.y);
        if (t != s) atomicMin(&best[t], (unsigned)q.y);
      }
    }
    __syncthreads();
    // ---- D: match winners ----
    for (int k = 0; k < K; ++k) {
      if ((candM[k >> 6] >> (k & 63)) & 1ULL) {
        int4 q = cur[tid + k * kMT];
        int s = q.x & 0xFFFF, t = q.x >> 16;
        if (best[s] == (unsigned)q.y && best[t] == (unsigned)q.y) {
          matM[k >> 6] |= 1ULL << (k & 63);
          atomicAnd(&avail[s >> 5], ~(1u << (s & 31)));
          atomicAnd(&avail[t >> 5], ~(1u << (t & 31)));
          cluster[t] = s;
          partner[s] = t;
          mult[s] = dec_f((unsigned)q.z);
        }
      }
    }
    if (tid == 0) sh_out = 0;
    __syncthreads();
    // ---- E: compact survivors + reset touched best cells ----
    for (int k = 0; k < K; ++k) {
      int i = tid + k * kMT;
      bool surv = false;
      int4 q = make_int4(0, 0, 0, 0);
      if (i < n) {
        q = cur[i];
        int s = q.x & 0xFFFF, t = q.x >> 16;
        best[s] = 0u;  // benign races: all writers store 0
        best[t] = 0u;
        bool lv = ((liveM[k >> 6] >> (k & 63)) & 1ULL) &&
                  !((matM[k >> 6] >> (k & 63)) & 1ULL);
        if (lv && ((avail[s >> 5] >> (s & 31)) & 1u) &&
            ((avail[t >> 5] >> (t & 31)) & 1u))
          surv = true;
      }
      ull mb = __ballot(surv);
      if (mb) {
        int leader = __ffsll(mb) - 1;
        int base = 0;
        if (lane == leader) base = atomicAdd(&sh_out, __popcll(mb));
        base = __shfl(base, leader, 64);
        if (surv) nxt[base + __popcll(mb & ((1ULL << lane) - 1))] = q;
      }
    }
    __syncthreads();
    n = sh_out;
    int4* tmp = cur;
    cur = nxt;
    nxt = tmp;
    __syncthreads();
  }
}

// ---------------- fused merged-features + graph pooling ----------------------
__global__ __launch_bounds__(256) void k_newx_pool(
    const float* __restrict__ z, const int* __restrict__ cluster,
    const int* __restrict__ partner, const float* __restrict__ mult,
    const int* __restrict__ batch, float* __restrict__ zo,
    float* __restrict__ embs_g) {
  int tid = threadIdx.x;
  int d = tid & 63;
  int n0 = blockIdx.x * 128 + (tid >> 6) * 32;
  float acc = 0.f;
  int curg = -1;
  for (int k = 0; k < 32; ++k) {
    int n = n0 + k;
    if (n >= kN) break;
    int g = batch[n];
    if (g != curg) {
      if (curg >= 0 && acc != 0.f) atomicAdd(&embs_g[curg * 64 + d], acc);
      acc = 0.f;
      curg = g;
    }
    float v;
    if (cluster) {
      v = 0.f;
      if (cluster[n] == n) {
        v = z[(size_t)n * 64 + d];
        int p = partner[n];
        if (p >= 0 && p != n) v += z[(size_t)p * 64 + d];
        v *= mult[n];
      }
    } else {
      v = z[(size_t)n * 64 + d];
    }
    if (zo) zo[(size_t)n * 64 + d] = v;
    acc += v;
  }
  if (curg >= 0 && acc != 0.f) atomicAdd(&embs_g[curg * 64 + d], acc);
}

// ---------------- edge remap + hash-dedup ----------------
__global__ void k_remap(const int* __restrict__ esrc, const int* __restrict__ edst,
                        const int* __restrict__ cluster, const int* __restrict__ emask,
                        int* __restrict__ esrcn, int* __restrict__ edstn,
                        int* __restrict__ hkey, int* __restrict__ hmin,
                        int* __restrict__ hslot) {
  int e = blockIdx.x * 256 + threadIdx.x;
  if (e >= kE) return;
  int ns = cluster[esrc[e]];
  int nt = cluster[edst[e]];
  esrcn[e] = ns;
  edstn[e] = nt;
  if (emask && !emask[e]) return;
  int key = ns * kN + nt;
  unsigned h = (((unsigned)key * 2654435761u) >> 13) & (kHSZ - 1);
  while (true) {
    int old = atomicCAS(&hkey[h], -1, key);
    if (old == -1 || old == key) break;
    h = (h + 1) & (kHSZ - 1);
  }
  atomicMin(&hmin[h], e);
  hslot[e] = (int)h;
}

__global__ void k_dedup(const int* __restrict__ emask, const int* __restrict__ hmin,
                        const int* __restrict__ hslot, int* __restrict__ emaskn) {
  int e = blockIdx.x * 256 + threadIdx.x;
  if (e >= kE) return;
  int keep = 0;
  if (!emask || emask[e]) keep = (hmin[hslot[e]] == e) ? 1 : 0;
  emaskn[e] = keep;
}

// ---------------- final FC ----------------
__global__ void k_final(const float* __restrict__ embs, const float* __restrict__ Wfc,
                        const float* __restrict__ bfc, float* __restrict__ out) {
  int tid = threadIdx.x;
  if (tid >= kG * 10) return;
  int g = tid / 10, c = tid % 10;
  float acc = bfc[c];
  for (int l = 0; l < 3; ++l)
    for (int d = 0; d < 64; ++d)
      acc += embs[l * (kG * 64) + g * 64 + d] * Wfc[(l * 64 + d) * 10 + c];
  out[g * 10 + c] = acc;
}

extern "C" void kernel_launch(void* const* d_in, const int* in_sizes, int n_in,
                              void* d_out, int out_size, void* d_ws, size_t ws_size,
                              hipStream_t stream) {
  (void)in_sizes; (void)n_in; (void)out_size; (void)ws_size;
  const float* x = (const float*)d_in[0];
  const int* ei = (const int*)d_in[1];  // [2,E]: src = ei, dst = ei + kE
  const int* batch = (const int*)d_in[2];
  const float* Wemb = (const float*)d_in[3];
  const float* We = (const float*)d_in[4];
  const float* be = (const float*)d_in[5];
  const float* Wfc = (const float*)d_in[6];
  const float* bfc = (const float*)d_in[7];
  float* out = (float*)d_out;

  char* ws = (char*)d_ws;
  size_t off = 0;
  auto alloc = [&](size_t bytes) -> void* {
    void* p = ws + off;
    off = (off + bytes + 255) & ~(size_t)255;
    return p;
  };
  float* z0 = (float*)alloc((size_t)kN * 64 * 4);
  float* z1 = (float*)alloc((size_t)kN * 64 * 4);
  float* raws = (float*)alloc((size_t)kE * 4);
  float* an = (float*)alloc((size_t)kN * 4);
  float* bn = (float*)alloc((size_t)kN * 4);
  double* den = (double*)alloc((size_t)kN * 8);
  int* cluster = (int*)alloc((size_t)kN * 4);
  int* partner = (int*)alloc((size_t)kN * 4);
  float* mult = (float*)alloc((size_t)kN * 4);
  int* esrc1 = (int*)alloc((size_t)kE * 4);
  int* edst1 = (int*)alloc((size_t)kE * 4);
  int* emask1 = (int*)alloc((size_t)kE * 4);
  int4* wl0 = (int4*)alloc((size_t)kE * 16);
  int4* wl1 = (int4*)alloc((size_t)kE * 16);
  int* hkey = (int*)alloc((size_t)kHSZ * 4);
  int* hmin = (int*)alloc((size_t)kHSZ * 4);
  int* hslot = (int*)alloc((size_t)kE * 4);
  float* embs = (float*)alloc((size_t)3 * kG * 64 * 4);
  int* cnt = (int*)alloc(256);

  const int gE = (kE + 255) / 256;   // 938
  const int gNP = (kN + 127) / 128;  // 235
  const unsigned ldsBytes = (kN + kNW) * 4;  // ~124 KB dynamic LDS

  // ---------------- layer 1 ----------------
  k_init<<<512, 256, 0, stream>>>(cluster, partner, mult, den, cnt, hkey, hmin,
                                  embs, 1);
  k_embed<<<kN / 16, 256, 0, stream>>>(x, Wemb, z0);
  k_newx_pool<<<gNP, 256, 0, stream>>>(z0, nullptr, nullptr, nullptr, batch, nullptr,
                                       embs);  // embs[0]
  k_ab<<<480, 1024, 0, stream>>>(z0, We, 0, an, bn);
  k_rawe<<<gE, 256, 0, stream>>>(an, bn, be, 0, ei, ei + kE, nullptr, raws, den);
  k_score<<<gE, 256, 0, stream>>>(raws, den, ei, ei + kE, nullptr, wl0, cnt);
  k_matchL<<<1, kMT, ldsBytes, stream>>>(wl0, wl1, cnt, cluster, partner, mult);
  k_newx_pool<<<gNP, 256, 0, stream>>>(z0, cluster, partner, mult, batch, z1,
                                       embs + kG * 64);  // z1 + embs[1]
  k_remap<<<gE, 256, 0, stream>>>(ei, ei + kE, cluster, nullptr, esrc1, edst1, hkey,
                                  hmin, hslot);
  k_dedup<<<gE, 256, 0, stream>>>(nullptr, hmin, hslot, emask1);

  // ---------------- layer 2 ----------------
  k_init<<<512, 256, 0, stream>>>(cluster, partner, mult, den, cnt, hkey, hmin,
                                  embs, 0);
  k_ab<<<480, 1024, 0, stream>>>(z1, We, 1, an, bn);
  k_rawe<<<gE, 256, 0, stream>>>(an, bn, be, 1, esrc1, edst1, emask1, raws, den);
  k_score<<<gE, 256, 0, stream>>>(raws, den, esrc1, edst1, emask1, wl0, cnt);
  k_matchL<<<1, kMT, ldsBytes, stream>>>(wl0, wl1, cnt, cluster, partner, mult);
  k_newx_pool<<<gNP, 256, 0, stream>>>(z1, cluster, partner, mult, batch, nullptr,
                                       embs + 2 * kG * 64);  // embs[2]

  k_final<<<1, 640, 0, stream>>>(embs, Wfc, bfc, out);
}

// Round 10
// 1142.224 us; speedup vs baseline: 4.7722x; 2.5416x over previous
//
#include <hip/hip_runtime.h>
#include <math.h>

#define kN 30000
#define kE 240000
#define kG 64
#define kHSZ (1 << 19)
#define kNW 938            // ceil(30000/32)
#define kGrd 938           // sort grid: 938*256 = 240128 >= kE
#define kNP (kGrd * 256)   // padded element count
#define CHK 2048           // matcher chunk (2 edges/thread)

typedef unsigned long long ull;

__device__ __forceinline__ unsigned enc_f(float x) {
  unsigned u = __float_as_uint(x);
  return (u & 0x80000000u) ? ~u : (u | 0x80000000u);
}
__device__ __forceinline__ float dec_f(unsigned u) {
  u = (u & 0x80000000u) ? (u ^ 0x80000000u) : ~u;
  return __uint_as_float(u);
}

// ---------------- embed: z = x @ W_embed ----------------
__global__ __launch_bounds__(256) void k_embed(const float* __restrict__ x,
                                               const float* __restrict__ W,
                                               float* __restrict__ z) {
  __shared__ float sW[128 * 64];
  int tid = threadIdx.x;
  for (int i = tid; i < 128 * 64; i += 256) sW[i] = W[i];
  __syncthreads();
  int lane = tid & 63, sub = tid >> 6;
  int row0 = blockIdx.x * 16;
  for (int r = sub; r < 16; r += 4) {
    int n = row0 + r;
    if (n >= kN) continue;
    const float* xr = x + (size_t)n * 128;
    float acc = 0.f;
#pragma unroll
    for (int k = 0; k < 128; ++k) acc = fmaf(xr[k], sW[k * 64 + lane], acc);
    z[(size_t)n * 64 + lane] = acc;
  }
}

// ---------------- per-layer init ----------------
__global__ void k_init(int* __restrict__ cluster, int* __restrict__ partner,
                       float* __restrict__ mult, double* __restrict__ den,
                       int* __restrict__ cnt, int* __restrict__ hkey,
                       int* __restrict__ hmin, float* __restrict__ embs,
                       int layer1) {
  int S = gridDim.x * blockDim.x;
  for (int i = blockIdx.x * blockDim.x + threadIdx.x; i < kHSZ; i += S) {
    if (i < kN) {
      cluster[i] = i;
      partner[i] = -1;
      mult[i] = 1.f;
      den[i] = 0.0;
    }
    if (i < 8) cnt[i] = 0;
    if (layer1) {
      hkey[i] = -1;
      hmin[i] = 0x7fffffff;
      if (i < 3 * kG * 64) embs[i] = 0.f;
    }
  }
}

// ---------------- per-node half-dots ----------------
__global__ __launch_bounds__(1024) void k_ab(const float* __restrict__ z,
                                             const float* __restrict__ We,
                                             int layer, float* __restrict__ a,
                                             float* __restrict__ b) {
  int wid = (blockIdx.x * 1024 + threadIdx.x) >> 6;
  int lane = threadIdx.x & 63;
  int nw = (gridDim.x * 1024) >> 6;
  float wlo = We[layer * 128 + lane];
  float whi = We[layer * 128 + 64 + lane];
  for (int n = wid; n < kN; n += nw) {
    float zv = z[(size_t)n * 64 + lane];
    float fa = zv * wlo, fb = zv * whi;
#pragma unroll
    for (int m = 32; m > 0; m >>= 1) {
      fa += __shfl_xor(fa, m, 64);
      fb += __shfl_xor(fb, m, 64);
    }
    if (lane == 0) {
      a[n] = fa;
      b[n] = fb;
    }
  }
}

// ---------------- raw edge score + f64 denominator (no-max softmax) ----------
__global__ void k_rawe(const float* __restrict__ a, const float* __restrict__ b,
                       const float* __restrict__ be, int layer,
                       const int* __restrict__ esrc, const int* __restrict__ edst,
                       const int* __restrict__ emask, float* __restrict__ raws,
                       double* __restrict__ den) {
  int e = blockIdx.x * 256 + threadIdx.x;
  if (e >= kE) return;
  if (emask && !emask[e]) return;
  int t = edst[e];
  float raw = a[esrc[e]] + b[t] + be[layer];
  raws[e] = raw;
  atomicAdd(&den[t], exp((double)raw));  // |raw| << 709: no overflow
}

// ---------------- build sortable records ----------------
// rec = (~enc(score) << 32) | (s | t<<16). Ascending sort on hi 32 bits =
// (score desc); initial order is edge-id ascending, stable passes keep it
// = exact reference tie order. Dead/pad: ~0ULL (sorts last).
__global__ __launch_bounds__(256) void k_score(
    const float* __restrict__ raws, const double* __restrict__ den,
    const int* __restrict__ esrc, const int* __restrict__ edst,
    const int* __restrict__ emask, ull* __restrict__ recs, int* __restrict__ cnt) {
  int e = blockIdx.x * 256 + threadIdx.x;
  ull rec = ~0ULL;
  bool live = false;
  if (e < kE && (!emask || emask[e])) {
    int s = esrc[e], t = edst[e];
    double ex = exp((double)raws[e]);
    float ep = (float)(ex / den[t]) + 0.5f;
    unsigned enc = enc_f(ep);
    rec = ((ull)(~enc) << 32) | (unsigned)(s | (t << 16));
    live = true;
  }
  recs[e] = rec;
  ull mb = __ballot(live);
  if ((threadIdx.x & 63) == 0 && mb) atomicAdd(cnt, (int)__popcll(mb));
}

// ---------------- radix sort pass: histogram ----------------
__global__ __launch_bounds__(256) void k_hist(const ull* __restrict__ in,
                                              unsigned* __restrict__ hist,
                                              int shift) {
  __shared__ unsigned h[256];
  int tid = threadIdx.x;
  h[tid] = 0;
  __syncthreads();
  unsigned d = (unsigned)(in[blockIdx.x * 256 + tid] >> shift) & 255u;
  atomicAdd(&h[d], 1u);
  __syncthreads();
  hist[blockIdx.x * 256 + tid] = h[tid];
}

// ---------------- radix sort pass: scan (1 WG) ----------------
__global__ __launch_bounds__(256) void k_scan(unsigned* __restrict__ hist,
                                              unsigned* __restrict__ digitBase) {
  __shared__ unsigned col[256];
  int d = threadIdx.x;
  unsigned run = 0;
  for (int g = 0; g < kGrd; ++g) {
    unsigned v = hist[g * 256 + d];
    hist[g * 256 + d] = run;  // exclusive prefix over blocks, per digit
    run += v;
  }
  col[d] = run;
  __syncthreads();
  if (d == 0) {
    unsigned acc = 0;
    for (int i = 0; i < 256; ++i) {
      unsigned t = col[i];
      col[i] = acc;
      acc += t;
    }
  }
  __syncthreads();
  digitBase[d] = col[d];
}

// ---------------- radix sort pass: stable scatter ----------------
__global__ __launch_bounds__(256) void k_scatter(const ull* __restrict__ in,
                                                 ull* __restrict__ out,
                                                 const unsigned* __restrict__ hist,
                                                 const unsigned* __restrict__ digitBase,
                                                 int shift) {
  __shared__ unsigned whist[4][256];
  int tid = threadIdx.x, w = tid >> 6, lane = tid & 63;
  for (int k = tid; k < 1024; k += 256) ((unsigned*)whist)[k] = 0;
  __syncthreads();
  ull rec = in[blockIdx.x * 256 + tid];
  unsigned d = (unsigned)(rec >> shift) & 255u;
  ull m = ~0ULL;
#pragma unroll
  for (int b = 0; b < 8; ++b) {
    ull bb = __ballot((d >> b) & 1u);
    m &= ((d >> b) & 1u) ? bb : ~bb;
  }
  int rank = __popcll(m & ((1ULL << lane) - 1ULL));
  int leader = __ffsll(m) - 1;
  if (lane == leader) whist[w][d] = (unsigned)__popcll(m);
  __syncthreads();
  unsigned wp = 0;
  for (int w2 = 0; w2 < w; ++w2) wp += whist[w2][d];
  unsigned dest = digitBase[d] + hist[blockIdx.x * 256 + d] + wp + (unsigned)rank;
  out[dest] = rec;
}

// ---------------- exact sequential-greedy matcher (single WG, LDS) ----------
// Sorted chunks of 2048. Epoch-tagged claims: claim[node] holds
// (epoch<<12)|(2047-pos) via atomicMax; stale epochs are dominated
// automatically (no reset phase, no plain-store races). Winner = holds its
// own pk at both endpoints = min chunk position among undecided -> exact
// sequential greedy. Only __syncthreads() + LDS atomics (r8-proven set).
__global__ __launch_bounds__(1024) void k_matchS(const ull* __restrict__ recs,
                                                 const int* __restrict__ cnt,
                                                 int* __restrict__ cluster,
                                                 int* __restrict__ partner,
                                                 float* __restrict__ mult) {
  extern __shared__ unsigned lds[];
  unsigned* claim = lds;       // [kN], init 0; pk always > 0
  unsigned* avail = lds + kN;  // [kNW]
  __shared__ int sh_any[2];
  const int tid = threadIdx.x;
  for (int i = tid; i < kN; i += 1024) claim[i] = 0u;
  for (int w = tid; w < kNW; w += 1024) {
    int rem = kN - (w << 5);
    avail[w] = (rem >= 32) ? ~0u : ((1u << rem) - 1u);
  }
  if (tid == 0) { sh_any[0] = 0; sh_any[1] = 0; }
  __syncthreads();
  const int nlive = cnt[0];
  const int nch = (nlive + CHK - 1) / CHK;
  unsigned epoch = 1;  // max ~118*4000 < 2^20 -> (epoch<<12) never overflows
  for (int c = 0; c < nch; ++c) {
    const int base = c * CHK;
    int s[2] = {0, 0}, t[2] = {0, 0};
    unsigned en[2] = {0, 0};
    int done[2];
#pragma unroll
    for (int k = 0; k < 2; ++k) {
      int gi = base + 2 * tid + k;
      done[k] = 1;
      if (gi < nlive) {
        ull rec = recs[gi];
        unsigned lo = (unsigned)rec;
        s[k] = lo & 0xFFFF;
        t[k] = (lo >> 16) & 0xFFFF;
        en[k] = ~((unsigned)(rec >> 32));
        done[k] = 0;
      }
    }
    for (int iter = 0; iter < 4000; ++iter, ++epoch) {
      // P: death-check + epoch-tagged claim posts
      unsigned pk[2];
      int posted = 0;
#pragma unroll
      for (int k = 0; k < 2; ++k) {
        pk[k] = 0;
        if (done[k]) continue;
        if (!((avail[s[k] >> 5] >> (s[k] & 31)) & 1u) ||
            !((avail[t[k] >> 5] >> (t[k] & 31)) & 1u)) {
          done[k] = 1;
          continue;
        }
        pk[k] = (epoch << 12) | (unsigned)(2047 - (2 * tid + k));
        atomicMax(&claim[s[k]], pk[k]);
        atomicMax(&claim[t[k]], pk[k]);
        posted = 1;
      }
      if (posted) sh_any[epoch & 1] = 1;          // benign same-value race
      if (tid == 0) sh_any[(epoch + 1) & 1] = 0;  // pre-zero next parity
      __syncthreads();
      if (!sh_any[epoch & 1]) break;  // uniform: nobody posted this epoch
      // W: winners hold their own pk at both endpoints
#pragma unroll
      for (int k = 0; k < 2; ++k) {
        if (!pk[k]) continue;
        if (claim[s[k]] == pk[k] && claim[t[k]] == pk[k]) {
          atomicAnd(&avail[s[k] >> 5], ~(1u << (s[k] & 31)));
          atomicAnd(&avail[t[k] >> 5], ~(1u << (t[k] & 31)));
          cluster[t[k]] = s[k];
          partner[s[k]] = t[k];
          mult[s[k]] = dec_f(en[k]);
          done[k] = 1;
        }
      }
      __syncthreads();
    }
  }
}

// ---------------- fused merged-features + graph pooling ----------------
__global__ __launch_bounds__(256) void k_newx_pool(
    const float* __restrict__ z, const int* __restrict__ cluster,
    const int* __restrict__ partner, const float* __restrict__ mult,
    const int* __restrict__ batch, float* __restrict__ zo,
    float* __restrict__ embs_g) {
  int tid = threadIdx.x;
  int d = tid & 63;
  int n0 = blockIdx.x * 128 + (tid >> 6) * 32;
  float acc = 0.f;
  int curg = -1;
  for (int k = 0; k < 32; ++k) {
    int n = n0 + k;
    if (n >= kN) break;
    int g = batch[n];
    if (g != curg) {
      if (curg >= 0 && acc != 0.f) atomicAdd(&embs_g[curg * 64 + d], acc);
      acc = 0.f;
      curg = g;
    }
    float v;
    if (cluster) {
      v = 0.f;
      if (cluster[n] == n) {
        v = z[(size_t)n * 64 + d];
        int p = partner[n];
        if (p >= 0 && p != n) v += z[(size_t)p * 64 + d];
        v *= mult[n];
      }
    } else {
      v = z[(size_t)n * 64 + d];
    }
    if (zo) zo[(size_t)n * 64 + d] = v;
    acc += v;
  }
  if (curg >= 0 && acc != 0.f) atomicAdd(&embs_g[curg * 64 + d], acc);
}

// ---------------- edge remap + hash-dedup ----------------
__global__ void k_remap(const int* __restrict__ esrc, const int* __restrict__ edst,
                        const int* __restrict__ cluster, const int* __restrict__ emask,
                        int* __restrict__ esrcn, int* __restrict__ edstn,
                        int* __restrict__ hkey, int* __restrict__ hmin,
                        int* __restrict__ hslot) {
  int e = blockIdx.x * 256 + threadIdx.x;
  if (e >= kE) return;
  int ns = cluster[esrc[e]];
  int nt = cluster[edst[e]];
  esrcn[e] = ns;
  edstn[e] = nt;
  if (emask && !emask[e]) return;
  int key = ns * kN + nt;
  unsigned h = (((unsigned)key * 2654435761u) >> 13) & (kHSZ - 1);
  while (true) {
    int old = atomicCAS(&hkey[h], -1, key);
    if (old == -1 || old == key) break;
    h = (h + 1) & (kHSZ - 1);
  }
  atomicMin(&hmin[h], e);
  hslot[e] = (int)h;
}

__global__ void k_dedup(const int* __restrict__ emask, const int* __restrict__ hmin,
                        const int* __restrict__ hslot, int* __restrict__ emaskn) {
  int e = blockIdx.x * 256 + threadIdx.x;
  if (e >= kE) return;
  int keep = 0;
  if (!emask || emask[e]) keep = (hmin[hslot[e]] == e) ? 1 : 0;
  emaskn[e] = keep;
}

// ---------------- final FC ----------------
__global__ void k_final(const float* __restrict__ embs, const float* __restrict__ Wfc,
                        const float* __restrict__ bfc, float* __restrict__ out) {
  int tid = threadIdx.x;
  if (tid >= kG * 10) return;
  int g = tid / 10, c = tid % 10;
  float acc = bfc[c];
  for (int l = 0; l < 3; ++l)
    for (int d = 0; d < 64; ++d)
      acc += embs[l * (kG * 64) + g * 64 + d] * Wfc[(l * 64 + d) * 10 + c];
  out[g * 10 + c] = acc;
}

extern "C" void kernel_launch(void* const* d_in, const int* in_sizes, int n_in,
                              void* d_out, int out_size, void* d_ws, size_t ws_size,
                              hipStream_t stream) {
  (void)in_sizes; (void)n_in; (void)out_size; (void)ws_size;
  const float* x = (const float*)d_in[0];
  const int* ei = (const int*)d_in[1];  // [2,E]: src = ei, dst = ei + kE
  const int* batch = (const int*)d_in[2];
  const float* Wemb = (const float*)d_in[3];
  const float* We = (const float*)d_in[4];
  const float* be = (const float*)d_in[5];
  const float* Wfc = (const float*)d_in[6];
  const float* bfc = (const float*)d_in[7];
  float* out = (float*)d_out;

  char* ws = (char*)d_ws;
  size_t off = 0;
  auto alloc = [&](size_t bytes) -> void* {
    void* p = ws + off;
    off = (off + bytes + 255) & ~(size_t)255;
    return p;
  };
  float* z0 = (float*)alloc((size_t)kN * 64 * 4);
  float* z1 = (float*)alloc((size_t)kN * 64 * 4);
  float* raws = (float*)alloc((size_t)kE * 4);
  float* an = (float*)alloc((size_t)kN * 4);
  float* bn = (float*)alloc((size_t)kN * 4);
  double* den = (double*)alloc((size_t)kN * 8);
  ull* recsA = (ull*)alloc((size_t)kNP * 8);
  ull* recsB = (ull*)alloc((size_t)kNP * 8);
  unsigned* hist = (unsigned*)alloc((size_t)kGrd * 256 * 4);
  unsigned* digitBase = (unsigned*)alloc(256 * 4);
  int* cluster = (int*)alloc((size_t)kN * 4);
  int* partner = (int*)alloc((size_t)kN * 4);
  float* mult = (float*)alloc((size_t)kN * 4);
  int* esrc1 = (int*)alloc((size_t)kE * 4);
  int* edst1 = (int*)alloc((size_t)kE * 4);
  int* emask1 = (int*)alloc((size_t)kE * 4);
  int* hkey = (int*)alloc((size_t)kHSZ * 4);
  int* hmin = (int*)alloc((size_t)kHSZ * 4);
  int* hslot = (int*)alloc((size_t)kE * 4);
  float* embs = (float*)alloc((size_t)3 * kG * 64 * 4);
  int* cnt = (int*)alloc(256);

  const int gE = (kE + 255) / 256;   // 938
  const int gNP = (kN + 127) / 128;  // 235
  const unsigned ldsBytes = (kN + kNW) * 4;  // ~124 KB dynamic LDS

  // ---------------- layer 1 ----------------
  k_init<<<512, 256, 0, stream>>>(cluster, partner, mult, den, cnt, hkey, hmin,
                                  embs, 1);
  k_embed<<<kN / 16, 256, 0, stream>>>(x, Wemb, z0);
  k_newx_pool<<<gNP, 256, 0, stream>>>(z0, nullptr, nullptr, nullptr, batch, nullptr,
                                       embs);  // embs[0]
  k_ab<<<480, 1024, 0, stream>>>(z0, We, 0, an, bn);
  k_rawe<<<gE, 256, 0, stream>>>(an, bn, be, 0, ei, ei + kE, nullptr, raws, den);
  k_score<<<kGrd, 256, 0, stream>>>(raws, den, ei, ei + kE, nullptr, recsA, cnt);
  // stable LSD radix over score bytes (bits 32..63)
  k_hist<<<kGrd, 256, 0, stream>>>(recsA, hist, 32);
  k_scan<<<1, 256, 0, stream>>>(hist, digitBase);
  k_scatter<<<kGrd, 256, 0, stream>>>(recsA, recsB, hist, digitBase, 32);
  k_hist<<<kGrd, 256, 0, stream>>>(recsB, hist, 40);
  k_scan<<<1, 256, 0, stream>>>(hist, digitBase);
  k_scatter<<<kGrd, 256, 0, stream>>>(recsB, recsA, hist, digitBase, 40);
  k_hist<<<kGrd, 256, 0, stream>>>(recsA, hist, 48);
  k_scan<<<1, 256, 0, stream>>>(hist, digitBase);
  k_scatter<<<kGrd, 256, 0, stream>>>(recsA, recsB, hist, digitBase, 48);
  k_hist<<<kGrd, 256, 0, stream>>>(recsB, hist, 56);
  k_scan<<<1, 256, 0, stream>>>(hist, digitBase);
  k_scatter<<<kGrd, 256, 0, stream>>>(recsB, recsA, hist, digitBase, 56);
  k_matchS<<<1, 1024, ldsBytes, stream>>>(recsA, cnt, cluster, partner, mult);
  k_newx_pool<<<gNP, 256, 0, stream>>>(z0, cluster, partner, mult, batch, z1,
                                       embs + kG * 64);  // z1 + embs[1]
  k_remap<<<gE, 256, 0, stream>>>(ei, ei + kE, cluster, nullptr, esrc1, edst1, hkey,
                                  hmin, hslot);
  k_dedup<<<gE, 256, 0, stream>>>(nullptr, hmin, hslot, emask1);

  // ---------------- layer 2 ----------------
  k_init<<<512, 256, 0, stream>>>(cluster, partner, mult, den, cnt, hkey, hmin,
                                  embs, 0);
  k_ab<<<480, 1024, 0, stream>>>(z1, We, 1, an, bn);
  k_rawe<<<gE, 256, 0, stream>>>(an, bn, be, 1, esrc1, edst1, emask1, raws, den);
  k_score<<<kGrd, 256, 0, stream>>>(raws, den, esrc1, edst1, emask1, recsA, cnt);
  k_hist<<<kGrd, 256, 0, stream>>>(recsA, hist, 32);
  k_scan<<<1, 256, 0, stream>>>(hist, digitBase);
  k_scatter<<<kGrd, 256, 0, stream>>>(recsA, recsB, hist, digitBase, 32);
  k_hist<<<kGrd, 256, 0, stream>>>(recsB, hist, 40);
  k_scan<<<1, 256, 0, stream>>>(hist, digitBase);
  k_scatter<<<kGrd, 256, 0, stream>>>(recsB, recsA, hist, digitBase, 40);
  k_hist<<<kGrd, 256, 0, stream>>>(recsA, hist, 48);
  k_scan<<<1, 256, 0, stream>>>(hist, digitBase);
  k_scatter<<<kGrd, 256, 0, stream>>>(recsA, recsB, hist, digitBase, 48);
  k_hist<<<kGrd, 256, 0, stream>>>(recsB, hist, 56);
  k_scan<<<1, 256, 0, stream>>>(hist, digitBase);
  k_scatter<<<kGrd, 256, 0, stream>>>(recsB, recsA, hist, digitBase, 56);
  k_matchS<<<1, 1024, ldsBytes, stream>>>(recsA, cnt, cluster, partner, mult);
  k_newx_pool<<<gNP, 256, 0, stream>>>(z1, cluster, partner, mult, batch, nullptr,
                                       embs + 2 * kG * 64);  // embs[2]

  k_final<<<1, 640, 0, stream>>>(embs, Wfc, bfc, out);
}